// Round 1
// baseline (213.558 us; speedup 1.0000x reference)
//
#include <hip/hip_runtime.h>

#define C_DIM 19
#define G_DIM 8
#define H_DIM 512
#define W_DIM 512
#define B_DIM 4
#define TILE  32
#define HALO  (TILE + 2)
#define PLANE (H_DIM * W_DIM)

__global__ __launch_bounds__(256, 4)
void gacrf_fused(const float* __restrict__ F,
                 const float* __restrict__ logit,
                 const float* __restrict__ matrix,
                 float* __restrict__ out)
{
    __shared__ float E_lds[G_DIM][C_DIM];          // 608 B
    __shared__ float Qg[G_DIM][HALO][HALO];        // 36992 B

    const int tid = threadIdx.x;
    const int bx  = blockIdx.x;    // 0..15  (w tiles)
    const int by  = blockIdx.y;    // 0..15  (h tiles)
    const int b   = blockIdx.z;    // 0..3

    // ---- E = softmax(100*matrix, axis=g), shape [G][C] ----
    if (tid < C_DIM) {
        const int c = tid;
        float m[G_DIM];
        float mx = -1e30f;
        #pragma unroll
        for (int g = 0; g < G_DIM; ++g) {
            m[g] = 100.0f * matrix[g * C_DIM + c];
            mx = fmaxf(mx, m[g]);
        }
        float s = 0.0f;
        #pragma unroll
        for (int g = 0; g < G_DIM; ++g) { m[g] = __expf(m[g] - mx); s += m[g]; }
        const float inv = 1.0f / s;
        #pragma unroll
        for (int g = 0; g < G_DIM; ++g) E_lds[g][c] = m[g] * inv;
    }
    __syncthreads();

    const int y0 = by * TILE - 1;
    const int x0 = bx * TILE - 1;
    const float* __restrict__ logit_b = logit + (size_t)b * C_DIM * PLANE;

    // ---- phase 1: Qg (softmax over C, encode to G) for 34x34 halo ----
    for (int idx = tid; idx < HALO * HALO; idx += 256) {
        const int hy = idx / HALO;
        const int hx = idx - hy * HALO;
        const int gy = y0 + hy;
        const int gx = x0 + hx;

        float eg[G_DIM];
        #pragma unroll
        for (int g = 0; g < G_DIM; ++g) eg[g] = 0.0f;

        if (gy >= 0 && gy < H_DIM && gx >= 0 && gx < W_DIM) {
            const float* __restrict__ p = logit_b + (size_t)gy * W_DIM + gx;
            float lv[C_DIM];
            float mx = -1e30f;
            #pragma unroll
            for (int c = 0; c < C_DIM; ++c) {
                lv[c] = p[(size_t)c * PLANE];
                mx = fmaxf(mx, lv[c]);
            }
            float s = 0.0f;
            #pragma unroll
            for (int c = 0; c < C_DIM; ++c) {
                const float e = __expf(lv[c] - mx);
                s += e;
                #pragma unroll
                for (int g = 0; g < G_DIM; ++g)
                    eg[g] = fmaf(E_lds[g][c], e, eg[g]);
            }
            const float inv = 1.0f / s;
            #pragma unroll
            for (int g = 0; g < G_DIM; ++g) eg[g] *= inv;
        }
        #pragma unroll
        for (int g = 0; g < G_DIM; ++g) Qg[g][hy][hx] = eg[g];
    }
    __syncthreads();

    // ---- phase 2: 3x3 dynamic filter + decode + subtract ----
    for (int idx = tid; idx < TILE * TILE; idx += 256) {
        const int ty = idx >> 5;
        const int tx = idx & 31;
        const int gy = by * TILE + ty;
        const int gx = bx * TILE + tx;
        const size_t pix = (size_t)gy * W_DIM + gx;

        const float* __restrict__ Fp = F + (size_t)b * 9 * PLANE + pix;

        float og[G_DIM];
        #pragma unroll
        for (int g = 0; g < G_DIM; ++g) og[g] = 0.0f;

        #pragma unroll
        for (int k = 0; k < 9; ++k) {
            const float wk = Fp[(size_t)k * PLANE];
            const int dy = k / 3;
            const int dx = k - dy * 3;
            #pragma unroll
            for (int g = 0; g < G_DIM; ++g)
                og[g] = fmaf(wk, Qg[g][ty + dy][tx + dx], og[g]);
        }

        const float* __restrict__ lp = logit_b + pix;
        float* __restrict__ op = out + (size_t)b * C_DIM * PLANE + pix;
        #pragma unroll
        for (int c = 0; c < C_DIM; ++c) {
            float dec = 0.0f;
            #pragma unroll
            for (int g = 0; g < G_DIM; ++g)
                dec = fmaf(E_lds[g][c], og[g], dec);
            op[(size_t)c * PLANE] = lp[(size_t)c * PLANE] - dec;
        }
    }
}

extern "C" void kernel_launch(void* const* d_in, const int* in_sizes, int n_in,
                              void* d_out, int out_size, void* d_ws, size_t ws_size,
                              hipStream_t stream) {
    const float* F      = (const float*)d_in[0];   // [4, 9, 512, 512]
    const float* logit  = (const float*)d_in[1];   // [4, 19, 512, 512]
    const float* matrix = (const float*)d_in[2];   // [8, 19, 1, 1]
    float* out = (float*)d_out;                    // [4, 19, 512, 512]

    dim3 grid(W_DIM / TILE, H_DIM / TILE, B_DIM);  // (16, 16, 4)
    gacrf_fused<<<grid, 256, 0, stream>>>(F, logit, matrix, out);
}